// Round 7
// baseline (133.436 us; speedup 1.0000x reference)
//
#include <hip/hip_runtime.h>

// out[m,n] = prod_d softplus(min(Zm,Ze)-max(zm,ze)) / softplus(Zm-zm)
//
// v8 = v7 with ONE isolated change: the compute loop is explicitly
// software-pipelined 1-d-ahead. v7 post-mortem: VALU busy-time invariant
// ~62us; per-pipe floors VALU-full ~17us, trans ~17-33us, LDS ~38us, and
// measured 77us ~= their SUM -> pipes serialized within waves. The old
// `#pragma unroll 1` chunk loop issued 24 ds_reads, drained, then ran a
// ~1024cy VALU burst -- at 4 waves/SIMD (2 blocks/CU) cross-wave overlap
// can't fill both pipes. v8 prefetches d+1's three float4s into NAMED
// registers before computing d's 8 FDs (peeled last iter), so LDS and
// VALU/trans interleave inside every scheduling window.
// Falsifier: if dur is flat, per-wave ILP isn't the blocker -> pivot to a
// 3-block/CU occupancy config next.
//
// Structure (v6/v7): single-phase stage -> 1 barrier -> compute -> store;
// BM=64 BN=64, 512 threads, 2x4/thread; LDS 64KB (2 blocks/CU);
// men (e^Zm,e^-zm) interleaved float2 [d][m]; entity split arrays [d][n];
// lane->row conflict-free entity staging; row denominator in registers
// (shfl_xor mul-reduce at staging).
//
// Math per unit (identical numerics to v1..v7, absmax 5.6e-17):
//   u = min(Em,Ee)*min(Im,Ie) = e^{min(Zm,Ze)-max(zm,ze)};
//   p *= log2(1+u); ln2^64 cancels between numerator and denominator;
//   final scale by full-row 1/prod_d log2(1+e^{Zm-zm}).

#define BM 64
#define BN 64
#define DD 64

// one fused-dim unit: p *= log2(1 + minE*minI)  -- raw v_log_f32
#define FD(PIJ, EMc, IMc, EEc, IEc) \
    PIJ *= __builtin_amdgcn_logf(__builtin_fmaf(fminf(EMc, EEc), fminf(IMc, IEc), 1.0f));

// all 8 FD units for one d, given the three resident float4s
#define FD8(MF, EE, IE) \
    FD(p[0][0], MF.x, MF.y, EE.x, IE.x) \
    FD(p[0][1], MF.x, MF.y, EE.y, IE.y) \
    FD(p[0][2], MF.x, MF.y, EE.z, IE.z) \
    FD(p[0][3], MF.x, MF.y, EE.w, IE.w) \
    FD(p[1][0], MF.z, MF.w, EE.x, IE.x) \
    FD(p[1][1], MF.z, MF.w, EE.y, IE.y) \
    FD(p[1][2], MF.z, MF.w, EE.z, IE.z) \
    FD(p[1][3], MF.z, MF.w, EE.w, IE.w)

__global__ __launch_bounds__(512, 4)
void ivr_kernel(const float* __restrict__ men, const float* __restrict__ en,
                float* __restrict__ out, int M, int N) {
    __shared__ __align__(16) float2 sMen[DD][BM];  // (e^{Zm}, e^{-zm}) [d][m] 32 KB
    __shared__ __align__(16) float  sEe[DD][BN];   // e^{Ze}   [d][n]          16 KB
    __shared__ __align__(16) float  sIe[DD][BN];   // e^{-ze}                  16 KB

    const int tx = threadIdx.x;
    const int m0 = blockIdx.y * BM;
    const int n0 = blockIdx.x * BN;

    // ---- men staging + in-register row denominator ----
    // thread -> (row ml = tx>>3, 8-d chunk dcM = (tx&7)*8); 8 threads/row
    float rden;
    {
        const int ml  = tx >> 3;         // 0..63
        const int dcM = (tx & 7) * 8;    // this thread's 8 d's
        int mm = m0 + ml; if (mm >= M) mm = M - 1;
        const float* r = men + (size_t)mm * 128 + dcM;
        const float4 z0 = *reinterpret_cast<const float4*>(r);        // z (min)
        const float4 z1 = *reinterpret_cast<const float4*>(r + 4);
        const float4 Z0 = *reinterpret_cast<const float4*>(r + 64);   // Z (max)
        const float4 Z1 = *reinterpret_cast<const float4*>(r + 68);
        float Em, Im, prod;
#define MSTG(K, ZV, ZZ) { Em = __expf(ZZ); Im = __expf(-(ZV)); \
        sMen[dcM + (K)][ml] = make_float2(Em, Im); \
        prod *= __builtin_amdgcn_logf(__builtin_fmaf(Em, Im, 1.0f)); }
        Em = __expf(Z0.x); Im = __expf(-z0.x);
        sMen[dcM + 0][ml] = make_float2(Em, Im);
        prod = __builtin_amdgcn_logf(__builtin_fmaf(Em, Im, 1.0f));
        MSTG(1, z0.y, Z0.y) MSTG(2, z0.z, Z0.z) MSTG(3, z0.w, Z0.w)
        MSTG(4, z1.x, Z1.x) MSTG(5, z1.y, Z1.y) MSTG(6, z1.z, Z1.z) MSTG(7, z1.w, Z1.w)
#undef MSTG
        // multiply-reduce the 8 per-thread partials of this row (8-aligned
        // lane group within one wave)
        prod *= __shfl_xor(prod, 1);
        prod *= __shfl_xor(prod, 2);
        prod *= __shfl_xor(prod, 4);
        rden = 1.0f / prod;              // full-row 1/denominator
    }
    // ---- entity staging: lane -> row (conflict-free LDS writes) ----
    // thread -> (row nl = tx&63, 8-d chunk dcE = (tx>>6)*8, wave-uniform)
    {
        const int nl  = tx & 63;
        const int dcE = (tx >> 6) * 8;
        int nn = n0 + nl; if (nn >= N) nn = N - 1;
        const float* r = en + (size_t)nn * 128 + dcE;
        const float4 z0 = *reinterpret_cast<const float4*>(r);
        const float4 z1 = *reinterpret_cast<const float4*>(r + 4);
        const float4 Z0 = *reinterpret_cast<const float4*>(r + 64);
        const float4 Z1 = *reinterpret_cast<const float4*>(r + 68);
#define ESTG(K, ZV, ZZ) { sEe[dcE + (K)][nl] = __expf(ZZ); \
                          sIe[dcE + (K)][nl] = __expf(-(ZV)); }
        ESTG(0, z0.x, Z0.x) ESTG(1, z0.y, Z0.y) ESTG(2, z0.z, Z0.z) ESTG(3, z0.w, Z0.w)
        ESTG(4, z1.x, Z1.x) ESTG(5, z1.y, Z1.y) ESTG(6, z1.z, Z1.z) ESTG(7, z1.w, Z1.w)
#undef ESTG
    }
    __syncthreads();

    const int ni = (tx & 15) * 4;        // 16 n-groups of 4
    const int mi = (tx >> 4) * 2;        // 32 m-pairs

    // row-denominator pair for (mi, mi+1): this thread staged row ml=tx>>3
    // = mi + hib; partner lane tx^8 staged the sibling row.
    const float oden = __shfl_xor(rden, 8);
    const int hib = (tx >> 3) & 1;
    const float rd0 = hib ? oden : rden;
    const float rd1 = hib ? rden : oden;

    float p[2][4];
    #pragma unroll
    for (int i = 0; i < 2; ++i)
        #pragma unroll
        for (int j = 0; j < 4; ++j) p[i][j] = 1.0f;

    // ---- compute: software-pipelined 1-d-ahead over all 64 d ----
    float4 mf  = *reinterpret_cast<const float4*>(&sMen[0][mi]);  // Em0,Im0,Em1,Im1
    float4 Ee4 = *reinterpret_cast<const float4*>(&sEe[0][ni]);
    float4 Ie4 = *reinterpret_cast<const float4*>(&sIe[0][ni]);
    #pragma unroll 8
    for (int d = 0; d < DD - 1; ++d) {
        const float4 mfn = *reinterpret_cast<const float4*>(&sMen[d + 1][mi]);
        const float4 Een = *reinterpret_cast<const float4*>(&sEe[d + 1][ni]);
        const float4 Ien = *reinterpret_cast<const float4*>(&sIe[d + 1][ni]);
        FD8(mf, Ee4, Ie4)
        mf = mfn; Ee4 = Een; Ie4 = Ien;
    }
    FD8(mf, Ee4, Ie4)                    // peeled d = 63

    #pragma unroll
    for (int j = 0; j < 4; ++j) { p[0][j] *= rd0; p[1][j] *= rd1; }

    // ---- store: 2 rows x float4 per thread ----
    #pragma unroll
    for (int i = 0; i < 2; ++i) {
        const int m = m0 + mi + i;
        if (m >= M) continue;
        const int n = n0 + ni;
        if (n + 4 <= N) {
            *reinterpret_cast<float4*>(&out[(size_t)m * N + n]) =
                make_float4(p[i][0], p[i][1], p[i][2], p[i][3]);
        } else {
            #pragma unroll
            for (int j = 0; j < 4; ++j)
                if (n + j < N) out[(size_t)m * N + n + j] = p[i][j];
        }
    }
}

extern "C" void kernel_launch(void* const* d_in, const int* in_sizes, int n_in,
                              void* d_out, int out_size, void* d_ws, size_t ws_size,
                              hipStream_t stream) {
    const float* men = (const float*)d_in[0];
    const float* en  = (const float*)d_in[1];
    float* out = (float*)d_out;
    const int M = in_sizes[0] / 128;   // 256
    const int N = in_sizes[1] / 128;   // 20000
    dim3 grid((N + BN - 1) / BN, (M + BM - 1) / BM);
    ivr_kernel<<<grid, dim3(512), 0, stream>>>(men, en, out, M, N);
}